// Round 6
// baseline (50245.102 us; speedup 1.0000x reference)
//
#include <hip/hip_runtime.h>
#include <math.h>

#define T_STEPS 200
#define BATCH   64
#define VOCAB   256
#define EMB     512
#define HN      1024
#define ON_     1024
#define SDIM    4096   // 4*HN
#define NBLK    256
#define BHN     (BATCH * HN)   // 65536
#define NGRP    8
#define GSZ     (NBLK / NGRP)  // 32

__device__ __forceinline__ float sigmoidf_(float x) {
    return 1.0f / (1.0f + __expf(-x));
}

// ---------------------------------------------------------------------------
// Hierarchical grid barrier, monotonic counters (init to 0 once per dispatch).
// 32 arrivals per group line + 8 leaders on one global line; s_sleep backoff.
// No threadfence: h-data moved via device-scope stores; arrival RMW is the
// release point (acq_rel atomic drains vmcnt), poll load is the acquire.
// ---------------------------------------------------------------------------
__device__ __forceinline__ void grid_barrier(int* bar, int step, int bid) {
    __syncthreads();
    if (threadIdx.x == 0) {
        const int g = bid & 7;
        int* lcnt = bar + g * 32;            // one 128B line per group
        int* lgen = bar + (8 + g) * 32;
        int* gcnt = bar + 16 * 32;
        int* ggen = bar + 17 * 32;
        int a = __hip_atomic_fetch_add(lcnt, 1, __ATOMIC_ACQ_REL, __HIP_MEMORY_SCOPE_AGENT);
        if (a == GSZ * (step + 1) - 1) {     // last arriver in group -> leader
            int b = __hip_atomic_fetch_add(gcnt, 1, __ATOMIC_ACQ_REL, __HIP_MEMORY_SCOPE_AGENT);
            if (b == NGRP * (step + 1) - 1) {
                __hip_atomic_store(ggen, step + 1, __ATOMIC_RELEASE, __HIP_MEMORY_SCOPE_AGENT);
            } else {
                while (__hip_atomic_load(ggen, __ATOMIC_ACQUIRE, __HIP_MEMORY_SCOPE_AGENT) <= step)
                    __builtin_amdgcn_s_sleep(2);
            }
            __hip_atomic_store(lgen, step + 1, __ATOMIC_RELEASE, __HIP_MEMORY_SCOPE_AGENT);
        } else {
            while (__hip_atomic_load(lgen, __ATOMIC_ACQUIRE, __HIP_MEMORY_SCOPE_AGENT) <= step)
                __builtin_amdgcn_s_sleep(2);
        }
    }
    __syncthreads();
}

// ---------------------------------------------------------------------------
// Cell GEMM, BK=128. A: global->reg->LDS (float4, XOR-swizzled slots).
// W: global->reg direct (16 float4/lane, double-buffered 1 tile ahead),
// never touches LDS. 8-wave K-split: wave wv owns k in [wv*16, wv*16+16).
// ---------------------------------------------------------------------------
__device__ __forceinline__ void cell_gemm(
    const float* __restrict__ A1, int K1,
    const float* __restrict__ A2, int K2,
    const float* __restrict__ W, int NKB, int colbase,
    int tid, int wv, int lane,
    float4 (*As4)[16], float (&acc)[4][4])
{
    const int rg = tid >> 5;        // A-staging row-group 0..15 (rows 4rg..4rg+3)
    const int kc = tid & 31;        // A-staging k-chunk 0..31 (k 4kc..4kc+3)
    const int Lp = lane & 15;       // compute row-group
    const int g4 = lane >> 4;       // gate 0..3
    const int wv4 = wv << 2;
    const float* wbase = W + (size_t)g4 * HN + colbase;

    float4 pa[4];
    float4 wfA[16], wfB[16];

    auto issueA = [&](int kb) {
        const int kk = kb << 7;
        const float* Ab; int koff, astr;
        if (kk < K1) { Ab = A1; koff = kk;      astr = K1; }
        else         { Ab = A2; koff = kk - K1; astr = K2; }
        const float* p = Ab + (size_t)(rg << 2) * astr + koff + (kc << 2);
        #pragma unroll
        for (int i = 0; i < 4; ++i)
            pa[i] = *(const float4*)(p + (size_t)i * astr);
    };
    auto commitA = [&]() {
        const int k0 = kc << 2;
        const int sp = rg ^ (kc & 15);   // XOR swizzle: write ~4-way, read ~2-way
        As4[k0 + 0][sp] = make_float4(pa[0].x, pa[1].x, pa[2].x, pa[3].x);
        As4[k0 + 1][sp] = make_float4(pa[0].y, pa[1].y, pa[2].y, pa[3].y);
        As4[k0 + 2][sp] = make_float4(pa[0].z, pa[1].z, pa[2].z, pa[3].z);
        As4[k0 + 3][sp] = make_float4(pa[0].w, pa[1].w, pa[2].w, pa[3].w);
    };
    auto issueW = [&](int kb, float4 (&wf)[16]) {
        const float* p = wbase + (size_t)((kb << 7) + (wv << 4)) * SDIM;
        #pragma unroll
        for (int q = 0; q < 16; ++q)
            wf[q] = *(const float4*)(p + (size_t)q * SDIM);
    };
    auto compute = [&](const float4 (&wf)[16]) {
        #pragma unroll
        for (int q = 0; q < 16; ++q) {
            const int k = (wv << 4) + q;
            const int sp = Lp ^ ((wv4 + (q >> 2)) & 15);
            float4 a4 = As4[k][sp];
            float4 w4 = wf[q];
            acc[0][0] = fmaf(a4.x, w4.x, acc[0][0]);
            acc[0][1] = fmaf(a4.x, w4.y, acc[0][1]);
            acc[0][2] = fmaf(a4.x, w4.z, acc[0][2]);
            acc[0][3] = fmaf(a4.x, w4.w, acc[0][3]);
            acc[1][0] = fmaf(a4.y, w4.x, acc[1][0]);
            acc[1][1] = fmaf(a4.y, w4.y, acc[1][1]);
            acc[1][2] = fmaf(a4.y, w4.z, acc[1][2]);
            acc[1][3] = fmaf(a4.y, w4.w, acc[1][3]);
            acc[2][0] = fmaf(a4.z, w4.x, acc[2][0]);
            acc[2][1] = fmaf(a4.z, w4.y, acc[2][1]);
            acc[2][2] = fmaf(a4.z, w4.z, acc[2][2]);
            acc[2][3] = fmaf(a4.z, w4.w, acc[2][3]);
            acc[3][0] = fmaf(a4.w, w4.x, acc[3][0]);
            acc[3][1] = fmaf(a4.w, w4.y, acc[3][1]);
            acc[3][2] = fmaf(a4.w, w4.z, acc[3][2]);
            acc[3][3] = fmaf(a4.w, w4.w, acc[3][3]);
        }
    };

    issueA(0);
    issueW(0, wfA);

    for (int kb = 0; kb < NKB; kb += 2) {   // NKB even (12 or 16)
        __syncthreads();                    // prev readers done with As4
        commitA();
        __syncthreads();                    // tile kb visible
        issueA(kb + 1);
        issueW(kb + 1, wfB);
        compute(wfA);
        __syncthreads();
        commitA();
        __syncthreads();
        if (kb + 2 < NKB) { issueA(kb + 2); issueW(kb + 2, wfA); }
        compute(wfB);
    }
    __syncthreads();   // As4 free before any LDS reuse
}

// deterministic 8-wave partial reduce into Sx
__device__ __forceinline__ void cell_reduce(
    int tid, int wv, int lane,
    float (*Pred)[64][17], float (*Sx)[66], const float (&acc)[4][4])
{
    #pragma unroll
    for (int i = 0; i < 4; ++i)
        #pragma unroll
        for (int j = 0; j < 4; ++j)
            Pred[wv][lane][(i << 2) + j] = acc[i][j];
    __syncthreads();
    #pragma unroll
    for (int u = 0; u < 2; ++u) {
        int e = (tid << 1) + u;
        int p = e >> 4, ij = e & 15;
        float v = 0.0f;
        #pragma unroll
        for (int w = 0; w < 8; ++w) v += Pred[w][p][ij];   // fixed order
        int i = ij >> 2, j = ij & 3;
        int rr = ((p & 15) << 2) + i;
        int cl = ((p >> 4) << 2) + j;
        Sx[cl][rr] = v;
    }
    __syncthreads();
}

// ---------------------------------------------------------------------------
// Persistent 2-layer LSTM. Block owns 4 h-cols (XCD-contiguous assignment).
// h-state: write-once-per-address slots (h0h[t], HS[t]) via device-scope
// stores -> no stale-L2 hazard for plain cached reads, W lines untouched.
// One hierarchical barrier per step.
// ---------------------------------------------------------------------------
__global__ __launch_bounds__(512, 2)
void lstm_persistent(const float* __restrict__ emb,
                     const float* __restrict__ h0_in,
                     const float* __restrict__ c0_in,
                     const float* __restrict__ h1_in,
                     const float* __restrict__ c1_in,
                     const float* __restrict__ W0, const float* __restrict__ b0v,
                     const float* __restrict__ W1, const float* __restrict__ b1v,
                     float* __restrict__ h0h,   // T * BHN  (aliases 'hid')
                     float* __restrict__ HS,    // T * BHN  (h1 outputs)
                     int* bar)
{
    __shared__ float4 As4[128][16];      // 32 KB
    __shared__ float  Pred[8][64][17];   // 34.8 KB
    __shared__ float  Sx[16][66];        //  4.2 KB

    const int tid  = threadIdx.x;
    const int wv   = tid >> 6;
    const int lane = tid & 63;

    const int xcd  = blockIdx.x & 7;
    const int slot = blockIdx.x >> 3;
    const int colbase = (xcd << 7) + (slot << 2);   // XCD owns 128 consecutive cols

    const int gr = tid >> 2;   // gate-phase row
    const int gi = tid & 3;    // gate-phase local col

    float c0r = 0.0f, c1r = 0.0f;
    float bf0[4], bf1[4];
    if (tid < 256) {
        c0r = c0_in[gr * HN + colbase + gi];
        c1r = c1_in[gr * HN + colbase + gi];
        #pragma unroll
        for (int gk = 0; gk < 4; ++gk) {
            bf0[gk] = b0v[gk * HN + colbase + gi];
            bf1[gk] = b1v[gk * HN + colbase + gi];
        }
    }

    for (int t = 0; t < T_STEPS; ++t) {
        const float* eT  = emb + (size_t)t * BATCH * EMB;
        const float* h0r = (t == 0) ? h0_in : h0h + (size_t)(t - 1) * BHN;
        float*       h0w = h0h + (size_t)t * BHN;
        const float* h1r = (t == 0) ? h1_in : HS + (size_t)(t - 1) * BHN;
        float*       h1w = HS + (size_t)t * BHN;

        // ---- layer 0 ----
        {
            float acc[4][4] = {};
            cell_gemm(eT, EMB, h0r, HN, W0, (EMB + HN) / 128, colbase,
                      tid, wv, lane, As4, acc);
            cell_reduce(tid, wv, lane, Pred, Sx, acc);
            if (tid < 256) {
                float fg = sigmoidf_(Sx[gi][gr]      + bf0[0]);
                float ig = sigmoidf_(Sx[4 + gi][gr]  + bf0[1]);
                float og = sigmoidf_(Sx[8 + gi][gr]  + bf0[2]);
                float gg = tanhf(    Sx[12 + gi][gr] + bf0[3]);
                c0r = fg * c0r + ig * gg;
                float hn = og * tanhf(c0r);
                __hip_atomic_store(&h0w[gr * HN + colbase + gi], hn,
                                   __ATOMIC_RELAXED, __HIP_MEMORY_SCOPE_AGENT);
            }
        }
        grid_barrier(bar, t, blockIdx.x);   // h0(t) visible device-wide

        // ---- layer 1 ----
        {
            float acc[4][4] = {};
            cell_gemm(h0w, HN, h1r, HN, W1, (HN + HN) / 128, colbase,
                      tid, wv, lane, As4, acc);
            cell_reduce(tid, wv, lane, Pred, Sx, acc);
            if (tid < 256) {
                float fg = sigmoidf_(Sx[gi][gr]      + bf1[0]);
                float ig = sigmoidf_(Sx[4 + gi][gr]  + bf1[1]);
                float og = sigmoidf_(Sx[8 + gi][gr]  + bf1[2]);
                float gg = tanhf(    Sx[12 + gi][gr] + bf1[3]);
                c1r = fg * c1r + ig * gg;
                float hn = og * tanhf(c1r);
                __hip_atomic_store(&h1w[gr * HN + colbase + gi], hn,
                                   __ATOMIC_RELAXED, __HIP_MEMORY_SCOPE_AGENT);
            }
        }
        // no second barrier: arrival at barrier(t+1) orders all h1(t) writes
        // before any block starts layer 1 of step t+1 (program order proof)
    }
}

// ---------------------------------------------------------------------------
// Parallel GEMM: C[M,N] = A[M,K] @ B[K,N] (+bias, opt relu). 128x64 tile.
// ---------------------------------------------------------------------------
__global__ __launch_bounds__(256)
void gemm128(const float* __restrict__ A, const float* __restrict__ B,
             const float* __restrict__ bias, float* __restrict__ C,
             int M, int N, int K, int relu)
{
    __shared__ float As[16][132];
    __shared__ float Bs[16][64];

    const int tid = threadIdx.x;
    const int tx = tid & 15, ty = tid >> 4;
    const int m0 = blockIdx.y << 7, n0 = blockIdx.x << 6;
    float acc[8][4] = {};

    for (int kk = 0; kk < K; kk += 16) {
        #pragma unroll
        for (int i = 0; i < 8; ++i) {
            int e = tid + (i << 8);
            int r = e >> 4, k = e & 15;
            As[k][r] = A[(size_t)(m0 + r) * K + kk + k];
        }
        #pragma unroll
        for (int i = 0; i < 4; ++i) {
            int e = tid + (i << 8);
            int r = e >> 6, c = e & 63;
            Bs[r][c] = B[(size_t)(kk + r) * N + n0 + c];
        }
        __syncthreads();
        #pragma unroll
        for (int k = 0; k < 16; ++k) {
            float4 a0 = *(const float4*)&As[k][(ty << 3)];
            float4 a1 = *(const float4*)&As[k][(ty << 3) + 4];
            float4 b4 = *(const float4*)&Bs[k][(tx << 2)];
            float a[8] = {a0.x, a0.y, a0.z, a0.w, a1.x, a1.y, a1.z, a1.w};
            float b[4] = {b4.x, b4.y, b4.z, b4.w};
            #pragma unroll
            for (int i = 0; i < 8; ++i)
                #pragma unroll
                for (int j = 0; j < 4; ++j)
                    acc[i][j] = fmaf(a[i], b[j], acc[i][j]);
        }
        __syncthreads();
    }

    #pragma unroll
    for (int i = 0; i < 8; ++i) {
        int gm = m0 + (ty << 3) + i;
        float4 o;
        float* op = (float*)&o;
        #pragma unroll
        for (int j = 0; j < 4; ++j) {
            int gn = n0 + (tx << 2) + j;
            float v = acc[i][j] + (bias ? bias[gn] : 0.0f);
            if (relu) v = fmaxf(v, 0.0f);
            op[j] = v;
        }
        *(float4*)&C[(size_t)gm * N + n0 + (tx << 2)] = o;
    }
}

__global__ void init_bar(int* bar) {
    int i = blockIdx.x * 256 + threadIdx.x;
    if (i < 1024) bar[i] = 0;
}

extern "C" void kernel_launch(void* const* d_in, const int* in_sizes, int n_in,
                              void* d_out, int out_size, void* d_ws, size_t ws_size,
                              hipStream_t stream) {
    const float* inputs     = (const float*)d_in[0];
    const float* h0_in      = (const float*)d_in[1];
    const float* c0_in      = (const float*)d_in[2];
    const float* h1_in      = (const float*)d_in[3];
    const float* c1_in      = (const float*)d_in[4];
    const float* emb_matrix = (const float*)d_in[5];
    const float* lstm_w0    = (const float*)d_in[6];
    const float* lstm_b0    = (const float*)d_in[7];
    const float* lstm_w1    = (const float*)d_in[8];
    const float* lstm_b1    = (const float*)d_in[9];
    const float* out_w0     = (const float*)d_in[10];
    const float* out_b0     = (const float*)d_in[11];
    const float* out_w1     = (const float*)d_in[12];
    const float* out_b1     = (const float*)d_in[13];
    float* logits = (float*)d_out;

    const int MB = T_STEPS * BATCH;  // 12800

    // workspace (floats): ~133 MB. NOTE: h0h aliases hid — hid is only
    // written AFTER the recurrence completes (out0 GEMM reads HS only).
    float* ws  = (float*)d_ws;
    float* emb = ws;                               // MB*EMB
    float* HS  = emb + (size_t)MB * EMB;           // T*BHN (h1 outputs)
    float* hid = HS  + (size_t)MB * HN;            // MB*ON_ (also h0 history)
    float* h0h = hid;                              // T*BHN == MB*ON_ exactly
    int*   bar = (int*)(hid + (size_t)MB * ON_);   // 1024 ints

    init_bar<<<dim3(4), 256, 0, stream>>>(bar);

    gemm128<<<dim3(EMB / 64, MB / 128), 256, 0, stream>>>(
        inputs, emb_matrix, nullptr, emb, MB, EMB, VOCAB, 0);

    lstm_persistent<<<dim3(NBLK), 512, 0, stream>>>(
        emb, h0_in, c0_in, h1_in, c1_in,
        lstm_w0, lstm_b0, lstm_w1, lstm_b1,
        h0h, HS, bar);

    gemm128<<<dim3(ON_ / 64, MB / 128), 256, 0, stream>>>(
        HS, out_w0, out_b0, hid, MB, ON_, HN, 1);

    gemm128<<<dim3(VOCAB / 64, MB / 128), 256, 0, stream>>>(
        hid, out_w1, out_b1, logits, MB, VOCAB, ON_, 0);
}

// Round 7
// 29385.349 us; speedup vs baseline: 1.7099x; 1.7099x over previous
//
#include <hip/hip_runtime.h>
#include <math.h>

#define T_STEPS 200
#define BATCH   64
#define VOCAB   256
#define EMB     512
#define HN      1024
#define ON_     1024
#define SDIM    4096   // 4*HN
#define NBLK    256
#define BHN     (BATCH * HN)   // 65536
#define NGRP    8
#define GSZ     (NBLK / NGRP)  // 32

__device__ __forceinline__ float sigmoidf_(float x) {
    return 1.0f / (1.0f + __expf(-x));
}

// ---------------------------------------------------------------------------
// Hierarchical grid barrier (256 blocks), monotonic counters, with
// __threadfence on both sides: release = L2 writeback of h stores,
// acquire = invalidate stale L1/L2 lines (R5-proven for slot reuse).
// ---------------------------------------------------------------------------
__device__ __forceinline__ void grid_barrier(int* bar, int step, int bid) {
    __syncthreads();
    if (threadIdx.x == 0) {
        __threadfence();
        const int g = bid & 7;
        int* lcnt = bar + g * 32;
        int* lgen = bar + (8 + g) * 32;
        int* gcnt = bar + 16 * 32;
        int* ggen = bar + 17 * 32;
        int a = __hip_atomic_fetch_add(lcnt, 1, __ATOMIC_ACQ_REL, __HIP_MEMORY_SCOPE_AGENT);
        if (a == GSZ * (step + 1) - 1) {
            int b = __hip_atomic_fetch_add(gcnt, 1, __ATOMIC_ACQ_REL, __HIP_MEMORY_SCOPE_AGENT);
            if (b == NGRP * (step + 1) - 1) {
                __hip_atomic_store(ggen, step + 1, __ATOMIC_RELEASE, __HIP_MEMORY_SCOPE_AGENT);
            } else {
                while (__hip_atomic_load(ggen, __ATOMIC_ACQUIRE, __HIP_MEMORY_SCOPE_AGENT) <= step)
                    __builtin_amdgcn_s_sleep(2);
            }
            __hip_atomic_store(lgen, step + 1, __ATOMIC_RELEASE, __HIP_MEMORY_SCOPE_AGENT);
        } else {
            while (__hip_atomic_load(lgen, __ATOMIC_ACQUIRE, __HIP_MEMORY_SCOPE_AGENT) <= step)
                __builtin_amdgcn_s_sleep(2);
        }
        __threadfence();
    }
    __syncthreads();
}

// 16 FMAs: acc[g] += s * wg (componentwise), g = 4 gates x 4 cols
__device__ __forceinline__ void fma16(float4 (&acc)[4], float s,
    const float4& w0, const float4& w1, const float4& w2, const float4& w3)
{
    acc[0].x = fmaf(s, w0.x, acc[0].x); acc[0].y = fmaf(s, w0.y, acc[0].y);
    acc[0].z = fmaf(s, w0.z, acc[0].z); acc[0].w = fmaf(s, w0.w, acc[0].w);
    acc[1].x = fmaf(s, w1.x, acc[1].x); acc[1].y = fmaf(s, w1.y, acc[1].y);
    acc[1].z = fmaf(s, w1.z, acc[1].z); acc[1].w = fmaf(s, w1.w, acc[1].w);
    acc[2].x = fmaf(s, w2.x, acc[2].x); acc[2].y = fmaf(s, w2.y, acc[2].y);
    acc[2].z = fmaf(s, w2.z, acc[2].z); acc[2].w = fmaf(s, w2.w, acc[2].w);
    acc[3].x = fmaf(s, w3.x, acc[3].x); acc[3].y = fmaf(s, w3.y, acc[3].y);
    acc[3].z = fmaf(s, w3.z, acc[3].z); acc[3].w = fmaf(s, w3.w, acc[3].w);
}

// ---------------------------------------------------------------------------
// K-segment GEMM, lane = batch row. A transposed [pairs][64][2]: one float2
// vload per pair. W wave-uniform -> SGPRs (scalar pipe), 1-pair lookahead.
// RS = W row stride (floats), GS = gate stride. acc[g] = 4 cols of gate g.
// ---------------------------------------------------------------------------
template<int RS, int GS>
__device__ __forceinline__ void gemm_seg(
    const float* __restrict__ AT,   // pair p, lane: AT[p*128 + lane*2 + {0,1}]
    const float* __restrict__ Wb,   // k row 0, block's col quad
    int npairs, int lane, float4 (&acc)[4])
{
    const float* ap = AT + lane * 2;
    const float* wp = Wb;
    float2 a   = *(const float2*)ap;
    float4 wa0 = *(const float4*)(wp + 0 * GS);
    float4 wa1 = *(const float4*)(wp + 1 * GS);
    float4 wa2 = *(const float4*)(wp + 2 * GS);
    float4 wa3 = *(const float4*)(wp + 3 * GS);
    float4 wb0 = *(const float4*)(wp + RS + 0 * GS);
    float4 wb1 = *(const float4*)(wp + RS + 1 * GS);
    float4 wb2 = *(const float4*)(wp + RS + 2 * GS);
    float4 wb3 = *(const float4*)(wp + RS + 3 * GS);
    for (int p = 0; p + 1 < npairs; ++p) {
        ap += 128;
        wp += 2 * RS;
        float2 an  = *(const float2*)ap;
        float4 na0 = *(const float4*)(wp + 0 * GS);
        float4 na1 = *(const float4*)(wp + 1 * GS);
        float4 na2 = *(const float4*)(wp + 2 * GS);
        float4 na3 = *(const float4*)(wp + 3 * GS);
        float4 nb0 = *(const float4*)(wp + RS + 0 * GS);
        float4 nb1 = *(const float4*)(wp + RS + 1 * GS);
        float4 nb2 = *(const float4*)(wp + RS + 2 * GS);
        float4 nb3 = *(const float4*)(wp + RS + 3 * GS);
        fma16(acc, a.x, wa0, wa1, wa2, wa3);
        fma16(acc, a.y, wb0, wb1, wb2, wb3);
        a = an;
        wa0 = na0; wa1 = na1; wa2 = na2; wa3 = na3;
        wb0 = nb0; wb1 = nb1; wb2 = nb2; wb3 = nb3;
    }
    fma16(acc, a.x, wa0, wa1, wa2, wa3);
    fma16(acc, a.y, wb0, wb1, wb2, wb3);
}

// ---------------------------------------------------------------------------
// Persistent 2-layer LSTM. Block owns 4 h-cols (XCD-contiguous).
// 8 waves split K contiguously; reduce via 36KB LDS; c in registers.
// All recurrent activations transposed-interleaved: [K/2][64][2].
// ---------------------------------------------------------------------------
__global__ __launch_bounds__(512, 2)
void lstm_persistent(const float* __restrict__ embT,   // [T][256][64][2]
                     const float* __restrict__ c0_in,
                     const float* __restrict__ c1_in,
                     const float* __restrict__ W0,     // (1536,4096) original
                     const float* __restrict__ b0v,
                     const float* __restrict__ Wp1,    // packed (NBLK,2048,16)
                     const float* __restrict__ b1v,
                     float* __restrict__ h0T,          // 2 ping-pong slots
                     float* __restrict__ HST,          // [T] slots: h1(t)
                     const float* __restrict__ h1iT,   // h1 init transposed
                     int* bar)
{
    __shared__ float4 Pred4[8][64][4];   // 32 KB
    __shared__ float4 Sx4[64][4];        //  4 KB

    const int tid  = threadIdx.x;
    const int wv   = tid >> 6;
    const int lane = tid & 63;
    const int xcd  = blockIdx.x & 7;
    const int slot = blockIdx.x >> 3;
    const int colbase = (xcd << 7) + (slot << 2);
    const float* wp1b = Wp1 + (size_t)blockIdx.x * (2048 * 16);

    const int gr = tid >> 2;   // gate-phase row
    const int gi = tid & 3;    // gate-phase local col

    float c0r = 0.0f, c1r = 0.0f;
    float4 bq0 = make_float4(0,0,0,0), bq1 = make_float4(0,0,0,0);
    if (tid < 256) {
        c0r = c0_in[gr * HN + colbase + gi];
        c1r = c1_in[gr * HN + colbase + gi];
        // reducer identity (r, g): bias quad of gate g
        bq0 = *(const float4*)(b0v + (tid & 3) * HN + colbase);
        bq1 = *(const float4*)(b1v + (tid & 3) * HN + colbase);
    }

    for (int t = 0; t < T_STEPS; ++t) {
        const float* h0prev = h0T + (size_t)((t + 1) & 1) * BHN;  // h0(t-1)
        float*       h0cur  = h0T + (size_t)(t & 1) * BHN;        // h0(t)
        const float* h1prev = (t == 0) ? h1iT : HST + (size_t)(t - 1) * BHN;
        float*       h1cur  = HST + (size_t)t * BHN;

        // ================= layer 0 =================
        {
            float4 acc[4] = {make_float4(0,0,0,0), make_float4(0,0,0,0),
                             make_float4(0,0,0,0), make_float4(0,0,0,0)};
            const int k0 = wv * 192, k1 = k0 + 192;
            int e1 = (k1 < EMB) ? k1 : EMB;
            if (e1 > k0)
                gemm_seg<SDIM, HN>(embT + (size_t)t * (EMB * BATCH) + (k0 >> 1) * 128,
                                   W0 + (size_t)k0 * SDIM + colbase,
                                   (e1 - k0) >> 1, lane, acc);
            int h0s = (k0 > EMB) ? k0 : EMB;
            if (k1 > h0s)
                gemm_seg<SDIM, HN>(h0prev + ((h0s - EMB) >> 1) * 128,
                                   W0 + (size_t)h0s * SDIM + colbase,
                                   (k1 - h0s) >> 1, lane, acc);
            // reduce + gates
            #pragma unroll
            for (int q = 0; q < 4; ++q) Pred4[wv][lane][q] = acc[q];
            __syncthreads();
            if (tid < 256) {
                int r = tid >> 2, g = tid & 3;
                float4 s = Pred4[0][r][g];
                #pragma unroll
                for (int w = 1; w < 8; ++w) {
                    float4 pw = Pred4[w][r][g];
                    s.x += pw.x; s.y += pw.y; s.z += pw.z; s.w += pw.w;
                }
                s.x += bq0.x; s.y += bq0.y; s.z += bq0.z; s.w += bq0.w;
                Sx4[r][g] = s;
            }
            __syncthreads();
            if (tid < 256) {
                const float* sx = (const float*)&Sx4[gr][0];
                float fg = sigmoidf_(sx[gi]);
                float ig = sigmoidf_(sx[4 + gi]);
                float og = sigmoidf_(sx[8 + gi]);
                float gg = tanhf(sx[12 + gi]);
                c0r = fg * c0r + ig * gg;
                float hn = og * tanhf(c0r);
                int cg = colbase + gi;
                h0cur[(cg >> 1) * 128 + gr * 2 + (cg & 1)] = hn;
            }
        }
        grid_barrier(bar, t, blockIdx.x);   // h0(t) visible device-wide

        // ================= layer 1 =================
        {
            float4 acc[4] = {make_float4(0,0,0,0), make_float4(0,0,0,0),
                             make_float4(0,0,0,0), make_float4(0,0,0,0)};
            const int k0 = wv * 256;
            // waves 0-3: h0(t) part; waves 4-7: h1(t-1) part (no split waves)
            const float* at = (wv < 4) ? (h0cur + (k0 >> 1) * 128)
                                       : (h1prev + ((k0 - HN) >> 1) * 128);
            gemm_seg<16, 4>(at, wp1b + (size_t)k0 * 16, 128, lane, acc);
            #pragma unroll
            for (int q = 0; q < 4; ++q) Pred4[wv][lane][q] = acc[q];
            __syncthreads();
            if (tid < 256) {
                int r = tid >> 2, g = tid & 3;
                float4 s = Pred4[0][r][g];
                #pragma unroll
                for (int w = 1; w < 8; ++w) {
                    float4 pw = Pred4[w][r][g];
                    s.x += pw.x; s.y += pw.y; s.z += pw.z; s.w += pw.w;
                }
                s.x += bq1.x; s.y += bq1.y; s.z += bq1.z; s.w += bq1.w;
                Sx4[r][g] = s;
            }
            __syncthreads();
            if (tid < 256) {
                const float* sx = (const float*)&Sx4[gr][0];
                float fg = sigmoidf_(sx[gi]);
                float ig = sigmoidf_(sx[4 + gi]);
                float og = sigmoidf_(sx[8 + gi]);
                float gg = tanhf(sx[12 + gi]);
                c1r = fg * c1r + ig * gg;
                float hn = og * tanhf(c1r);
                int cg = colbase + gi;
                h1cur[(cg >> 1) * 128 + gr * 2 + (cg & 1)] = hn;
            }
            __syncthreads();   // Sx4 consumed before next cell's reduce
        }
        // no second barrier: arrival at barrier(t+1) orders h1(t) stores
        // before any block's layer-1(t+1) reads (program-order proof)
    }
}

// ---------------------------------------------------------------------------
// Parallel GEMM: C[M,N] = A[M,K] @ B[K,N]. 128x64 tile, 8x4 micro.
// AMODE 0: plain row-major A. AMODE 1: A = HST transposed [T][K/2][64][2].
// CMODE 0: plain C + bias (+relu). CMODE 1: C = embT scatter [T][N/2][64][2].
// ---------------------------------------------------------------------------
template<int AMODE, int CMODE>
__global__ __launch_bounds__(256)
void gemm128(const float* __restrict__ A, const float* __restrict__ B,
             const float* __restrict__ bias, float* __restrict__ C,
             int M, int N, int K, int relu)
{
    __shared__ float As[16][132];
    __shared__ float Bs[16][64];

    const int tid = threadIdx.x;
    const int tx = tid & 15, ty = tid >> 4;
    const int m0 = blockIdx.y << 7, n0 = blockIdx.x << 6;
    float acc[8][4] = {};

    for (int kk = 0; kk < K; kk += 16) {
        if (AMODE == 0) {
            #pragma unroll
            for (int i = 0; i < 8; ++i) {
                int e = tid + (i << 8);
                int r = e >> 4, k = e & 15;
                As[k][r] = A[(size_t)(m0 + r) * K + kk + k];
            }
        } else {
            #pragma unroll
            for (int i = 0; i < 8; ++i) {
                int e = tid + (i << 8);
                int k = e >> 7, rr = e & 127;
                int gm = m0 + rr, tt = gm >> 6, b = gm & 63;
                As[k][rr] = A[(size_t)tt * BHN + ((kk + k) >> 1) * 128 + b * 2 + ((kk + k) & 1)];
            }
        }
        #pragma unroll
        for (int i = 0; i < 4; ++i) {
            int e = tid + (i << 8);
            int r = e >> 6, c = e & 63;
            Bs[r][c] = B[(size_t)(kk + r) * N + n0 + c];
        }
        __syncthreads();
        #pragma unroll
        for (int k = 0; k < 16; ++k) {
            float4 a0 = *(const float4*)&As[k][(ty << 3)];
            float4 a1 = *(const float4*)&As[k][(ty << 3) + 4];
            float4 b4 = *(const float4*)&Bs[k][(tx << 2)];
            float a[8] = {a0.x, a0.y, a0.z, a0.w, a1.x, a1.y, a1.z, a1.w};
            float b[4] = {b4.x, b4.y, b4.z, b4.w};
            #pragma unroll
            for (int i = 0; i < 8; ++i)
                #pragma unroll
                for (int j = 0; j < 4; ++j)
                    acc[i][j] = fmaf(a[i], b[j], acc[i][j]);
        }
        __syncthreads();
    }

    if (CMODE == 0) {
        #pragma unroll
        for (int i = 0; i < 8; ++i) {
            int gm = m0 + (ty << 3) + i;
            float4 o;
            float* op = (float*)&o;
            #pragma unroll
            for (int j = 0; j < 4; ++j) {
                int gn = n0 + (tx << 2) + j;
                float v = acc[i][j] + (bias ? bias[gn] : 0.0f);
                if (relu) v = fmaxf(v, 0.0f);
                op[j] = v;
            }
            *(float4*)&C[(size_t)gm * N + n0 + (tx << 2)] = o;
        }
    } else {
        // embT scatter: (t, n-pair, b, 2)
        #pragma unroll
        for (int i = 0; i < 8; ++i) {
            int gm = m0 + (ty << 3) + i;
            int tt = gm >> 6, b = gm & 63;
            float* base = C + (size_t)tt * (EMB * BATCH) + b * 2;
            int gn = n0 + (tx << 2);
            *(float2*)(base + (gn >> 1) * 128) = make_float2(acc[i][0], acc[i][1]);
            *(float2*)(base + ((gn + 2) >> 1) * 128) = make_float2(acc[i][2], acc[i][3]);
        }
    }
}

// pack W1 per block: Wp1[b][k][g*4+j] = W1[k][g*HN + colbase(b) + j]
__global__ __launch_bounds__(256)
void pack_w1(const float* __restrict__ W1, float* __restrict__ Wp1) {
    int idx = blockIdx.x * 256 + threadIdx.x;
    int c = idx & 15, k = (idx >> 4) & 2047, b = idx >> 15;
    int colbase = ((b & 7) << 7) + ((b >> 3) << 2);
    Wp1[idx] = W1[(size_t)k * SDIM + (c >> 2) * HN + colbase + (c & 3)];
}

// zero barrier + transpose initial h states
__global__ __launch_bounds__(256)
void init_misc(const float* __restrict__ h0_in, const float* __restrict__ h1_in,
               float* __restrict__ h0T, float* __restrict__ h1iT, int* bar) {
    int i = blockIdx.x * 256 + threadIdx.x;
    if (i < 1024) bar[i] = 0;
    if (i < BHN) {
        int b = i >> 10, col = i & 1023;
        int tj = (col >> 1) * 128 + b * 2 + (col & 1);
        h0T[BHN + tj] = h0_in[i];   // slot 1 = h0(-1)
        h1iT[tj] = h1_in[i];
    }
}

extern "C" void kernel_launch(void* const* d_in, const int* in_sizes, int n_in,
                              void* d_out, int out_size, void* d_ws, size_t ws_size,
                              hipStream_t stream) {
    const float* inputs     = (const float*)d_in[0];
    const float* h0_in      = (const float*)d_in[1];
    const float* c0_in      = (const float*)d_in[2];
    const float* h1_in      = (const float*)d_in[3];
    const float* c1_in      = (const float*)d_in[4];
    const float* emb_matrix = (const float*)d_in[5];
    const float* lstm_w0    = (const float*)d_in[6];
    const float* lstm_b0    = (const float*)d_in[7];
    const float* lstm_w1    = (const float*)d_in[8];
    const float* lstm_b1    = (const float*)d_in[9];
    const float* out_w0     = (const float*)d_in[10];
    const float* out_b0     = (const float*)d_in[11];
    const float* out_w1     = (const float*)d_in[12];
    const float* out_b1     = (const float*)d_in[13];
    float* logits = (float*)d_out;

    const int MB = T_STEPS * BATCH;  // 12800

    // workspace (floats), ~113 MB total:
    float* ws   = (float*)d_ws;
    float* embT = ws;                                   //  6,553,600
    float* Wp1  = embT + (size_t)T_STEPS * EMB * BATCH; //  8,388,608
    float* HST  = Wp1  + (size_t)2048 * 16 * NBLK;      // 13,107,200
    float* h0T  = HST  + (size_t)T_STEPS * BHN;         //    131,072
    float* h1iT = h0T  + 2 * (size_t)BHN;               //     65,536
    int*   bar  = (int*)(h1iT + (size_t)BHN);           //      1,024
    // hid aliases [embT .. Wp1+] — both dead after the recurrence
    float* hid  = ws;                                   // 13,107,200 < 14,942,208

    init_misc<<<dim3(256), 256, 0, stream>>>(h0_in, h1_in, h0T, h1iT, bar);
    pack_w1<<<dim3(32768), 256, 0, stream>>>(lstm_w1, Wp1);

    // embT = (inputs @ emb_matrix) transposed-interleaved
    gemm128<0, 1><<<dim3(EMB / 64, MB / 128), 256, 0, stream>>>(
        inputs, emb_matrix, nullptr, embT, MB, EMB, VOCAB, 0);

    lstm_persistent<<<dim3(NBLK), 512, 0, stream>>>(
        embT, c0_in, c1_in, lstm_w0, lstm_b0, Wp1, lstm_b1,
        h0T, HST, h1iT, bar);

    // hid = relu(HS @ out_w0 + out_b0), A read from transposed HST
    gemm128<1, 0><<<dim3(ON_ / 64, MB / 128), 256, 0, stream>>>(
        HST, out_w0, out_b0, hid, MB, ON_, HN, 1);

    // logits = hid @ out_w1 + out_b1
    gemm128<0, 0><<<dim3(VOCAB / 64, MB / 128), 256, 0, stream>>>(
        hid, out_w1, out_b1, logits, MB, VOCAB, ON_, 0);
}